// Round 8
// baseline (2229.302 us; speedup 1.0000x reference)
//
#include <hip/hip_runtime.h>
#include <math.h>

typedef _Float16 half_t;
typedef _Float16 half2_t __attribute__((ext_vector_type(2)));
typedef _Float16 half8_t __attribute__((ext_vector_type(8)));
typedef float float4_t __attribute__((ext_vector_type(4)));
typedef int int4v __attribute__((ext_vector_type(4)));

#define T_ 64
#define B_ 256
#define D_ 16
#define S_ 64
#define SP_ 68   // padded y-history row stride (floats)
#define H_ 128
#define O_ 8
#define NSTEP 63
#define NT 1024   // 16 waves: 2 samples x 8 waves (R7 post-mortem: need INDEPENDENT chains)
#define NG 2      // samples per block

// ws layout (bytes):
//   [0, 131072)        Wf3 int8, row-major [1024][128]
//   [131072, 135168)   swf float[1024] per-row weight scales (max|row|/127)
//   [135168, 151552)   Wf1 fp16 [128][64]
//   [151552, 184320)   Wf2 fp16 [128][128]
#define W3I_OFF 0
#define SWF_OFF 131072
#define W1_OFF  135168
#define W2_OFF  151552

#define H2B 8.0f   // clamp bound for h2 int8 quantization (derived bound ~3)

#define MFMA16(a, b, c) __builtin_amdgcn_mfma_f32_16x16x32_f16(a, b, c, 0, 0, 0)
#define MFMAI8(a, b, c) __builtin_amdgcn_mfma_i32_16x16x64_i8(a, b, c, 0, 0, 0)

// LDS-only barrier (R4-validated): wait ds ops, sync, fence compiler.
#define BAR_LDS() do { \
  asm volatile("s_waitcnt lgkmcnt(0)" ::: "memory"); \
  __builtin_amdgcn_s_barrier(); \
  asm volatile("" ::: "memory"); \
} while (0)

// DPP 16-lane butterfly add (VALU; validated)
#if __has_builtin(__builtin_amdgcn_mov_dpp)
#define DPP_ADD(x, ctrl) \
  ((x) + __int_as_float(__builtin_amdgcn_mov_dpp(__float_as_int(x), (ctrl), 0xF, 0xF, true)))
#else
#define DPP_ADD(x, ctrl) ((x) + __shfl_xor((x), (ctrl) == 0xB1 ? 1 : (ctrl) == 0x4E ? 2 : (ctrl) == 0x141 ? 4 : 8))
#endif

// AE[j] = coefficients on k[0..j] producing the NEXT stage input (j<5) or B_SOL (j==5)
__device__ constexpr float AE[6][6] = {
  {0.161f, 0.f, 0.f, 0.f, 0.f, 0.f},
  {-0.008480655492356989f, 0.335480655492357f, 0.f, 0.f, 0.f, 0.f},
  {2.8971530571054935f, -6.359448489975075f, 4.3622954328695815f, 0.f, 0.f, 0.f},
  {5.325864828439257f, -11.748883564062828f, 7.4955393428898365f, -0.09249506636175525f, 0.f, 0.f},
  {5.86145544294642f, -12.92096931784711f, 8.159367898576159f, -0.071584973281401f, -0.028269050394068383f, 0.f},
  {0.09646076681806523f, 0.01f, 0.4798896504144996f, 1.379008574103742f, -3.290069515436081f, 2.324710524099774f}
};
__device__ constexpr float CCn[6] = {0.f, 0.161f, 0.327f, 0.9f, 0.9800255409045097f, 1.f};

__device__ __forceinline__ float softplus_f(float x) {
  return fmaxf(x, 0.f) + __logf(1.f + __expf(-fabsf(x)));
}
__device__ __forceinline__ float tanh_f(float x) {
  float xc = fminf(fmaxf(x, -12.f), 12.f);
  float e = __expf(2.f * xc);
  return (e - 1.f) * __builtin_amdgcn_rcpf(e + 1.f);
}

// ---------------- prologue 1: Wf1/Wf2 fp32 -> fp16 ----------------
__global__ __launch_bounds__(256) void convert12_kernel(
    const float* __restrict__ Wf1, const float* __restrict__ Wf2,
    unsigned char* __restrict__ wsb)
{
  half_t* w1h = (half_t*)(wsb + W1_OFF);
  half_t* w2h = (half_t*)(wsb + W2_OFF);
  int q = blockIdx.x * 256 + threadIdx.x;
  if (q < 8192) w1h[q] = (half_t)Wf1[q];
  else if (q < 24576) w2h[q - 8192] = (half_t)Wf2[q - 8192];
}

// ---------------- prologue 2: Wf3 fp32 -> int8 with per-row scale ----------------
__global__ __launch_bounds__(256) void convert3_kernel(
    const float* __restrict__ Wf3, unsigned char* __restrict__ wsb)
{
  signed char* w3i = (signed char*)(wsb + W3I_OFF);
  float* swf = (float*)(wsb + SWF_OFF);
  const int tid = threadIdx.x;
  const int wid = tid >> 6;
  const int lane = tid & 63;
  const int row = blockIdx.x * 4 + wid;
  const float a0 = Wf3[row * H_ + 2 * lane];
  const float a1 = Wf3[row * H_ + 2 * lane + 1];
  float m = fmaxf(fabsf(a0), fabsf(a1));
  #pragma unroll
  for (int s = 1; s < 64; s <<= 1) m = fmaxf(m, __shfl_xor(m, s));
  const float sw = fmaxf(m, 1e-20f) * (1.0f / 127.0f);
  const float inv = 1.0f / sw;
  w3i[row * H_ + 2 * lane]     = (signed char)(int)floorf(a0 * inv + 0.5f);
  w3i[row * H_ + 2 * lane + 1] = (signed char)(int)floorf(a1 * inv + 0.5f);
  if (lane == 0) swf[row] = sw;
}

// ---------------- main kernel ----------------
// R5 arithmetic, 2 INDEPENDENT samples per block (128 blocks x 16 waves):
// waves 0-7 = sample A, waves 8-15 = sample B, per-sample LDS banks, identical
// per-sample code. Phases are barrier-locked across the pair (symmetric, harmless);
// within each phase every SIMD holds 4 waves carrying 2 independent dependency
// chains -> chain latency of one sample hides under the other's issue stream.
// Per-sample VALU/matrix totals identical to R5 (work conserved).
__global__ void __launch_bounds__(NT) __attribute__((amdgpu_waves_per_eu(4, 4)))
cde_kernel_i8p2(
    const float* __restrict__ ts,
    const float* __restrict__ coeff_d,
    const float* __restrict__ coeff_c,
    const float* __restrict__ coeff_b,
    const float* __restrict__ coeff_a,
    const float* __restrict__ Wi1, const float* __restrict__ bi1,
    const float* __restrict__ Wi2, const float* __restrict__ bi2,
    const float* __restrict__ bf1, const float* __restrict__ bf2,
    const float* __restrict__ bf3,
    const float* __restrict__ Wr, const float* __restrict__ br,
    const unsigned char* __restrict__ wsb,
    float* __restrict__ out)
{
  __shared__ __align__(16) half_t syj_h[NG][S_];
  __shared__ __align__(16) half_t sh1h[NG][H_];
  __shared__ __align__(16) unsigned char sh2b[NG][H_];   // h2 quantized int8 (0..127)
  __shared__ __align__(16) float shist[NG][T_][SP_];     // y history (padded rows)
  __shared__ float sWr[O_ * S_];
  __shared__ float sbr[O_];
  __shared__ float sx0[NG][D_];
  __shared__ float sini[NG][H_];
  __shared__ float shs[T_];

  const int tid = threadIdx.x;
  const int w = tid >> 6;          // wave 0..15
  const int g = w >> 3;            // sample group 0/1
  const int wg = w & 7;            // wave within group 0..7
  const int gt = tid & 511;        // thread index within group
  const int lane = tid & 63;
  const int q = lane >> 4;         // 16-lane row 0..3
  const int c = lane & 15;         // fragment column
  const int bg = blockIdx.x * NG + g;   // sample index

  const signed char* __restrict__ w3i = (const signed char*)(wsb + W3I_OFF);
  const float* __restrict__ swf = (const float*)(wsb + SWF_OFF);
  const half_t* __restrict__ w1p = (const half_t*)(wsb + W1_OFF);
  const half_t* __restrict__ w2p = (const half_t*)(wsb + W2_OFF);

  // ---- persistent B fragments (identical for both groups: same weights) ----
  const int n1 = 16 * wg + c;      // output column for h1/h2 tiles
  half8_t bW1[2], bW2[4];
  int4v bW3i[8][2];
  #pragma unroll
  for (int ks = 0; ks < 2; ++ks)
    bW1[ks] = *(const half8_t*)(w1p + n1 * S_ + ks * 32 + q * 8);
  #pragma unroll
  for (int ks = 0; ks < 4; ++ks)
    bW2[ks] = *(const half8_t*)(w2p + n1 * H_ + ks * 32 + q * 8);
  #pragma unroll
  for (int t = 0; t < 8; ++t) {
    const int r = 16 * (8 * wg + t) + c;   // Wf3 row for this tile/col
    #pragma unroll
    for (int ks = 0; ks < 2; ++ks)
      bW3i[t][ks] = *(const int4v*)(w3i + (size_t)r * H_ + ks * 64 + q * 16);
  }
  const float bf1r = bf1[n1];
  const float bf2r = bf2[n1];
  // epilogue rows this lane keeps: s0 = 8wg+2q, s1 = s0+1 (col c = d)
  const int s0 = 8 * wg + 2 * q;
  const float bf3r0 = bf3[16 * s0 + c];
  const float bf3r1 = bf3[16 * (s0 + 1) + c];
  const float sw0s = swf[16 * s0 + c] * (H2B / 127.0f);
  const float sw1s = swf[16 * (s0 + 1) + c] * (H2B / 127.0f);

  // ---- one-time staging + y0 (per group where sample-specific) ----
  if (tid < O_ * S_) sWr[tid] = Wr[tid];
  if (tid < O_) sbr[tid] = br[tid];
  if (tid < NSTEP) shs[tid] = ts[tid + 1] - ts[tid];
  if (gt < D_) sx0[g][gt] = coeff_a[(size_t)bg * NSTEP * D_ + gt];
  __syncthreads();
  if (gt < H_) {
    float acc = bi1[gt];
    #pragma unroll
    for (int d = 0; d < D_; ++d) acc += sx0[g][d] * Wi1[gt * D_ + d];
    sini[g][gt] = softplus_f(acc);
  }
  __syncthreads();
  if (gt < S_) {
    float acc = bi2[gt];
    for (int h = 0; h < H_; ++h) acc += sini[g][h] * Wi2[gt * H_ + h];
    shist[g][0][gt] = acc;
  }
  __syncthreads();

  // RK state wave-uniform per 16-lane row: all lanes of row q track y[s0], y[s0+1]
  float yr0 = shist[g][0][s0];
  float yr1 = shist[g][0][s0 + 1];
  float kr0[6] = {0.f,0.f,0.f,0.f,0.f,0.f};
  float kr1[6] = {0.f,0.f,0.f,0.f,0.f,0.f};
  if (c == 0) {
    half2_t p; p[0] = (half_t)yr0; p[1] = (half_t)yr1;
    *(half2_t*)(&syj_h[g][s0]) = p;
  }
  __syncthreads();

  const float4_t Zv = {0.f, 0.f, 0.f, 0.f};
  const int4v Zi = {0, 0, 0, 0};

  // coeff register pipeline (R4): values for step t in (cbv,ccv,cdv); prefetch t+1
  const size_t cbase = (size_t)bg * NSTEP * D_ + c;
  float cbv = coeff_b[cbase];
  float ccv = coeff_c[cbase];
  float cdv = coeff_d[cbase];

  // ---- time loop ----
  for (int t = 0; t < NSTEP; ++t) {
    const int tn = (t + 1 < NSTEP) ? (t + 1) : t;
    const size_t cidxn = cbase + (size_t)tn * D_;
    const float cbn = coeff_b[cidxn];
    const float ccn = coeff_c[cidxn];
    const float cdn = coeff_d[cidxn];

    const float hstep = shs[t];
    float dxj[6];
    #pragma unroll
    for (int j = 0; j < 6; ++j) {
      const float frac = CCn[j] * hstep;
      dxj[j] = cbv + frac * (2.f * ccv + 3.f * frac * cdv);
    }

    #pragma unroll
    for (int j = 0; j < 6; ++j) {
      // ---- h1: yj @ Wf1^T (K=64), fp16 MFMA ----
      {
        const half8_t* ap = (const half8_t*)&syj_h[g][0];
        half8_t a0 = ap[q];           // k = q*8 ..
        half8_t a1 = ap[4 + q];       // k = 32 + q*8 ..
        float4_t acc0 = MFMA16(a0, bW1[0], Zv);
        float4_t acc1 = MFMA16(a1, bW1[1], Zv);
        if (q == 0) sh1h[g][n1] = (half_t)softplus_f(acc0[0] + acc1[0] + bf1r);
      }
      BAR_LDS();   // B1

      // ---- h2: h1 @ Wf2^T (K=128), fp16 MFMA; output quantized to int8 ----
      {
        const half8_t* ap = (const half8_t*)&sh1h[g][0];
        half8_t a0 = ap[q], a1 = ap[4 + q], a2 = ap[8 + q], a3 = ap[12 + q];
        float4_t accA = MFMA16(a0, bW2[0], Zv);
        float4_t accB = MFMA16(a1, bW2[1], Zv);
        accA = MFMA16(a2, bW2[2], accA);
        accB = MFMA16(a3, bW2[3], accB);
        if (q == 0) {
          const float h2v = softplus_f(accA[0] + accB[0] + bf2r);
          const int qi = (int)(fminf(h2v, H2B) * (127.0f / H2B) + 0.5f);
          sh2b[g][n1] = (unsigned char)qi;
        }
      }
      BAR_LDS();   // B2

      // ---- GEMV3: int8 MFMA, 8 tiles x 2 K-slices ----
      {
        const int4v a0i = *(const int4v*)(&sh2b[g][0] + 16 * q);        // k = 0..63
        const int4v a1i = *(const int4v*)(&sh2b[g][0] + 64 + 16 * q);   // k = 64..127
        int4v iacc[8];
        #pragma unroll
        for (int tt = 0; tt < 8; ++tt) iacc[tt] = MFMAI8(a0i, bW3i[tt][0], Zi);
        #pragma unroll
        for (int tt = 0; tt < 8; ++tt) iacc[tt] = MFMAI8(a1i, bW3i[tt][1], iacc[tt]);

        // quad q consumes tiles 2q, 2q+1 (rows s0, s0+1 at col c)
        int i0, i1;
        if (q == 0)      { i0 = iacc[0][0]; i1 = iacc[1][0]; }
        else if (q == 1) { i0 = iacc[2][0]; i1 = iacc[3][0]; }
        else if (q == 2) { i0 = iacc[4][0]; i1 = iacc[5][0]; }
        else             { i0 = iacc[6][0]; i1 = iacc[7][0]; }
        const float v0 = (float)i0 * sw0s;
        const float v1 = (float)i1 * sw1s;

        const float dx = dxj[j];
        float p0 = tanh_f(v0 + bf3r0) * dx;
        float p1 = tanh_f(v1 + bf3r1) * dx;
        // 16-lane butterfly via DPP
        p0 = DPP_ADD(p0, 0xB1);   p1 = DPP_ADD(p1, 0xB1);
        p0 = DPP_ADD(p0, 0x4E);   p1 = DPP_ADD(p1, 0x4E);
        p0 = DPP_ADD(p0, 0x141);  p1 = DPP_ADD(p1, 0x141);
        p0 = DPP_ADD(p0, 0x140);  p1 = DPP_ADD(p1, 0x140);

        // wave-uniform RK arithmetic
        kr0[j] = p0;
        kr1[j] = p1;
        float sa0 = AE[j][0] * kr0[0];
        float sa1 = AE[j][0] * kr1[0];
        #pragma unroll
        for (int m = 1; m < 6; ++m) if (m <= j) { sa0 = fmaf(AE[j][m], kr0[m], sa0); sa1 = fmaf(AE[j][m], kr1[m], sa1); }
        float yn0 = fmaf(hstep, sa0, yr0);
        float yn1 = fmaf(hstep, sa1, yr1);
        if (j == 5) { yr0 = yn0; yr1 = yn1; }
        if (c == 0) {
          half2_t p; p[0] = (half_t)yn0; p[1] = (half_t)yn1;
          *(half2_t*)(&syj_h[g][s0]) = p;
          if (j == 5) {
            float2 f; f.x = yn0; f.y = yn1;
            *(float2*)(&shist[g][t + 1][s0]) = f;
          }
        }
      }
      BAR_LDS();   // B3
    }

    cbv = cbn; ccv = ccn; cdv = cdn;
  }

  // ---- batched projection epilogue: out[bg, t, o] for all 64 t x 8 o per group ----
  __syncthreads();
  {
    const int tt = gt >> 3;        // 0..63
    const int oo = gt & 7;         // 0..7
    const float4* yp = (const float4*)(&shist[g][tt][0]);
    const float4* wp = (const float4*)(sWr + oo * S_);
    float a0 = 0.f, a1 = 0.f;
    #pragma unroll
    for (int i = 0; i < 16; i += 2) {
      float4 y0 = yp[i], w0 = wp[i];
      float4 y1 = yp[i + 1], w1 = wp[i + 1];
      a0 += y0.x * w0.x + y0.y * w0.y + y0.z * w0.z + y0.w * w0.w;
      a1 += y1.x * w1.x + y1.y * w1.y + y1.z * w1.z + y1.w * w1.w;
    }
    out[((size_t)bg * T_ + tt) * O_ + oo] = a0 + a1 + sbr[oo];
  }
}

extern "C" void kernel_launch(void* const* d_in, const int* in_sizes, int n_in,
                              void* d_out, int out_size, void* d_ws, size_t ws_size,
                              hipStream_t stream) {
  const float* ts  = (const float*)d_in[0];
  const float* cd  = (const float*)d_in[1];
  const float* cc  = (const float*)d_in[2];
  const float* cb  = (const float*)d_in[3];
  const float* ca  = (const float*)d_in[4];
  const float* Wi1 = (const float*)d_in[5];
  const float* bi1 = (const float*)d_in[6];
  const float* Wi2 = (const float*)d_in[7];
  const float* bi2 = (const float*)d_in[8];
  const float* Wf1 = (const float*)d_in[9];
  const float* bf1 = (const float*)d_in[10];
  const float* Wf2 = (const float*)d_in[11];
  const float* bf2 = (const float*)d_in[12];
  const float* Wf3 = (const float*)d_in[13];
  const float* bf3 = (const float*)d_in[14];
  const float* Wr  = (const float*)d_in[15];
  const float* br  = (const float*)d_in[16];

  unsigned char* wsb = (unsigned char*)d_ws;
  hipLaunchKernelGGL(convert12_kernel, dim3(96), dim3(256), 0, stream, Wf1, Wf2, wsb);
  hipLaunchKernelGGL(convert3_kernel, dim3(256), dim3(256), 0, stream, Wf3, wsb);
  hipLaunchKernelGGL(cde_kernel_i8p2, dim3(B_ / NG), dim3(NT), 0, stream,
                     ts, cd, cc, cb, ca, Wi1, bi1, Wi2, bi2,
                     bf1, bf2, bf3, Wr, br, wsb, (float*)d_out);
}

// Round 9
// 460.224 us; speedup vs baseline: 4.8439x; 4.8439x over previous
//
#include <hip/hip_runtime.h>
#include <math.h>

typedef _Float16 half_t;
typedef _Float16 half2_t __attribute__((ext_vector_type(2)));
typedef _Float16 half8_t __attribute__((ext_vector_type(8)));
typedef float float4_t __attribute__((ext_vector_type(4)));
typedef int int4v __attribute__((ext_vector_type(4)));

#define T_ 64
#define B_ 256
#define D_ 16
#define S_ 64
#define SP_ 68   // padded y-history row stride (floats)
#define H_ 128
#define O_ 8
#define NSTEP 63
#define NT 512

// ws layout (bytes):
//   [0, 131072)        Wf3 int8, row-major [1024][128]
//   [131072, 135168)   swf float[1024] per-row weight scales (max|row|/127)
//   [135168, 151552)   Wf1 fp16 [128][64]
//   [151552, 184320)   Wf2 fp16 [128][128]
#define W3I_OFF 0
#define SWF_OFF 131072
#define W1_OFF  135168
#define W2_OFF  151552

#define H2B 8.0f   // clamp bound for h2 int8 quantization (derived bound ~3)

#define MFMA16(a, b, c) __builtin_amdgcn_mfma_f32_16x16x32_f16(a, b, c, 0, 0, 0)

// LDS-only barrier (R4-validated): wait ds ops, sync, fence compiler.
#define BAR_LDS() do { \
  asm volatile("s_waitcnt lgkmcnt(0)" ::: "memory"); \
  __builtin_amdgcn_s_barrier(); \
  asm volatile("" ::: "memory"); \
} while (0)

// DPP 16-lane butterfly add (VALU; validated)
#if __has_builtin(__builtin_amdgcn_mov_dpp)
#define DPP_ADD(x, ctrl) \
  ((x) + __int_as_float(__builtin_amdgcn_mov_dpp(__float_as_int(x), (ctrl), 0xF, 0xF, true)))
#else
#define DPP_ADD(x, ctrl) ((x) + __shfl_xor((x), (ctrl) == 0xB1 ? 1 : (ctrl) == 0x4E ? 2 : (ctrl) == 0x141 ? 4 : 8))
#endif

// v_dot4_i32_i8: acc += sum of 4 signed byte products (VALU, exact int)
#if __has_builtin(__builtin_amdgcn_sdot4)
__device__ __forceinline__ int dot4i(int a, int b, int acc) {
  return __builtin_amdgcn_sdot4(a, b, acc, false);
}
#else
__device__ __forceinline__ int dot4i(int a, int b, int acc) {
  asm("v_dot4_i32_i8 %0, %1, %2, %0" : "+v"(acc) : "v"(a), "v"(b));
  return acc;
}
#endif

// AE[j] = coefficients on k[0..j] producing the NEXT stage input (j<5) or B_SOL (j==5)
__device__ constexpr float AE[6][6] = {
  {0.161f, 0.f, 0.f, 0.f, 0.f, 0.f},
  {-0.008480655492356989f, 0.335480655492357f, 0.f, 0.f, 0.f, 0.f},
  {2.8971530571054935f, -6.359448489975075f, 4.3622954328695815f, 0.f, 0.f, 0.f},
  {5.325864828439257f, -11.748883564062828f, 7.4955393428898365f, -0.09249506636175525f, 0.f, 0.f},
  {5.86145544294642f, -12.92096931784711f, 8.159367898576159f, -0.071584973281401f, -0.028269050394068383f, 0.f},
  {0.09646076681806523f, 0.01f, 0.4798896504144996f, 1.379008574103742f, -3.290069515436081f, 2.324710524099774f}
};
__device__ constexpr float CCn[6] = {0.f, 0.161f, 0.327f, 0.9f, 0.9800255409045097f, 1.f};

__device__ __forceinline__ float softplus_f(float x) {
  return fmaxf(x, 0.f) + __logf(1.f + __expf(-fabsf(x)));
}
__device__ __forceinline__ float tanh_f(float x) {
  float xc = fminf(fmaxf(x, -12.f), 12.f);
  float e = __expf(2.f * xc);
  return (e - 1.f) * __builtin_amdgcn_rcpf(e + 1.f);
}

// ---------------- prologue 1: Wf1/Wf2 fp32 -> fp16 ----------------
__global__ __launch_bounds__(256) void convert12_kernel(
    const float* __restrict__ Wf1, const float* __restrict__ Wf2,
    unsigned char* __restrict__ wsb)
{
  half_t* w1h = (half_t*)(wsb + W1_OFF);
  half_t* w2h = (half_t*)(wsb + W2_OFF);
  int q = blockIdx.x * 256 + threadIdx.x;
  if (q < 8192) w1h[q] = (half_t)Wf1[q];
  else if (q < 24576) w2h[q - 8192] = (half_t)Wf2[q - 8192];
}

// ---------------- prologue 2: Wf3 fp32 -> int8 with per-row scale ----------------
__global__ __launch_bounds__(256) void convert3_kernel(
    const float* __restrict__ Wf3, unsigned char* __restrict__ wsb)
{
  signed char* w3i = (signed char*)(wsb + W3I_OFF);
  float* swf = (float*)(wsb + SWF_OFF);
  const int tid = threadIdx.x;
  const int wid = tid >> 6;
  const int lane = tid & 63;
  const int row = blockIdx.x * 4 + wid;
  const float a0 = Wf3[row * H_ + 2 * lane];
  const float a1 = Wf3[row * H_ + 2 * lane + 1];
  float m = fmaxf(fabsf(a0), fabsf(a1));
  #pragma unroll
  for (int s = 1; s < 64; s <<= 1) m = fmaxf(m, __shfl_xor(m, s));
  const float sw = fmaxf(m, 1e-20f) * (1.0f / 127.0f);
  const float inv = 1.0f / sw;
  w3i[row * H_ + 2 * lane]     = (signed char)(int)floorf(a0 * inv + 0.5f);
  w3i[row * H_ + 2 * lane + 1] = (signed char)(int)floorf(a1 * inv + 0.5f);
  if (lane == 0) swf[row] = sw;
}

// ---------------- main kernel ----------------
// R5 structure (8 waves, 2/SIMD, 512 threads) but GEMV3 is FULLY on v_dot4_i32_i8:
// MFMA-GEMV wastes 15/16 of each i8 matrix op (broadcast A-rows); dot4 delivers
// 128 useful MACs/cyc/SIMD with no wasted lanes and no quad-row select. Each lane
// holds the full K=128 int8 weights of its own two epilogue rows (64 VGPR, replacing
// the 64-reg bW3i + 32-reg iacc of the MFMA version). Integer accumulation is exact
// -> bit-identical results to R5 (absmax canary 0.00390625). h1/h2 stay on fp16 MFMA.
__global__ void __launch_bounds__(NT) __attribute__((amdgpu_waves_per_eu(2, 2)))
cde_kernel_i8d4(
    const float* __restrict__ ts,
    const float* __restrict__ coeff_d,
    const float* __restrict__ coeff_c,
    const float* __restrict__ coeff_b,
    const float* __restrict__ coeff_a,
    const float* __restrict__ Wi1, const float* __restrict__ bi1,
    const float* __restrict__ Wi2, const float* __restrict__ bi2,
    const float* __restrict__ bf1, const float* __restrict__ bf2,
    const float* __restrict__ bf3,
    const float* __restrict__ Wr, const float* __restrict__ br,
    const unsigned char* __restrict__ wsb,
    float* __restrict__ out)
{
  __shared__ __align__(16) half_t syj_h[S_];
  __shared__ __align__(16) half_t sh1h[H_];
  __shared__ __align__(16) unsigned char sh2b[H_];   // h2 quantized int8 (0..127)
  __shared__ __align__(16) float shist[T_][SP_];     // y history (padded rows)
  __shared__ float sWr[O_ * S_];
  __shared__ float sbr[O_];
  __shared__ float sx0[D_];
  __shared__ float sini[H_];
  __shared__ float shs[T_];

  const int tid = threadIdx.x;
  const int b = blockIdx.x;
  const int w = tid >> 6;          // wave 0..7
  const int lane = tid & 63;
  const int q = lane >> 4;         // 16-lane row 0..3
  const int c = lane & 15;         // fragment column

  const signed char* __restrict__ w3i = (const signed char*)(wsb + W3I_OFF);
  const float* __restrict__ swf = (const float*)(wsb + SWF_OFF);
  const half_t* __restrict__ w1p = (const half_t*)(wsb + W1_OFF);
  const half_t* __restrict__ w2p = (const half_t*)(wsb + W2_OFF);

  // ---- persistent B fragments (h1/h2 on MFMA) ----
  const int n1 = 16 * w + c;       // output column for h1/h2 tiles
  half8_t bW1[2], bW2[4];
  #pragma unroll
  for (int ks = 0; ks < 2; ++ks)
    bW1[ks] = *(const half8_t*)(w1p + n1 * S_ + ks * 32 + q * 8);
  #pragma unroll
  for (int ks = 0; ks < 4; ++ks)
    bW2[ks] = *(const half8_t*)(w2p + n1 * H_ + ks * 32 + q * 8);
  const float bf1r = bf1[n1];
  const float bf2r = bf2[n1];
  // epilogue rows this lane keeps: s0 = 8w+2q, s1 = s0+1 (col c = d)
  const int s0 = 8 * w + 2 * q;
  const float bf3r0 = bf3[16 * s0 + c];
  const float bf3r1 = bf3[16 * (s0 + 1) + c];
  const float sw0s = swf[16 * s0 + c] * (H2B / 127.0f);
  const float sw1s = swf[16 * (s0 + 1) + c] * (H2B / 127.0f);

  // ---- per-lane dot4 weights: FULL K=128 of this lane's two rows (32+32 regs) ----
  int w3t0[32], w3t1[32];
  {
    const int4v* p0 = (const int4v*)(w3i + (size_t)(16 * s0 + c) * H_);
    const int4v* p1 = (const int4v*)(w3i + (size_t)(16 * (s0 + 1) + c) * H_);
    #pragma unroll
    for (int i = 0; i < 8; ++i) {
      ((int4v*)w3t0)[i] = p0[i];
      ((int4v*)w3t1)[i] = p1[i];
    }
  }

  // ---- one-time staging + y0 ----
  if (tid < O_ * S_) sWr[tid] = Wr[tid];
  if (tid < O_) sbr[tid] = br[tid];
  if (tid < D_) sx0[tid] = coeff_a[(size_t)b * NSTEP * D_ + tid];
  if (tid < NSTEP) shs[tid] = ts[tid + 1] - ts[tid];
  __syncthreads();
  if (tid < H_) {
    float acc = bi1[tid];
    #pragma unroll
    for (int d = 0; d < D_; ++d) acc += sx0[d] * Wi1[tid * D_ + d];
    sini[tid] = softplus_f(acc);
  }
  __syncthreads();
  if (tid < S_) {
    float acc = bi2[tid];
    for (int h = 0; h < H_; ++h) acc += sini[h] * Wi2[tid * H_ + h];
    shist[0][tid] = acc;
  }
  __syncthreads();

  // RK state wave-uniform per 16-lane row: all lanes of row q track y[s0], y[s0+1]
  float yr0 = shist[0][s0];
  float yr1 = shist[0][s0 + 1];
  float kr0[6] = {0.f,0.f,0.f,0.f,0.f,0.f};
  float kr1[6] = {0.f,0.f,0.f,0.f,0.f,0.f};
  if (c == 0) {
    half2_t p; p[0] = (half_t)yr0; p[1] = (half_t)yr1;
    *(half2_t*)(syj_h + s0) = p;
  }
  __syncthreads();

  const float4_t Zv = {0.f, 0.f, 0.f, 0.f};

  // coeff register pipeline (R4): values for step t in (cbv,ccv,cdv); prefetch t+1
  const size_t cbase = (size_t)b * NSTEP * D_ + c;
  float cbv = coeff_b[cbase];
  float ccv = coeff_c[cbase];
  float cdv = coeff_d[cbase];

  // ---- time loop ----
  for (int t = 0; t < NSTEP; ++t) {
    const int tn = (t + 1 < NSTEP) ? (t + 1) : t;
    const size_t cidxn = cbase + (size_t)tn * D_;
    const float cbn = coeff_b[cidxn];
    const float ccn = coeff_c[cidxn];
    const float cdn = coeff_d[cidxn];

    const float hstep = shs[t];
    float dxj[6];
    #pragma unroll
    for (int j = 0; j < 6; ++j) {
      const float frac = CCn[j] * hstep;
      dxj[j] = cbv + frac * (2.f * ccv + 3.f * frac * cdv);
    }

    #pragma unroll
    for (int j = 0; j < 6; ++j) {
      // ---- h1: yj @ Wf1^T (K=64), fp16 MFMA ----
      {
        const half8_t* ap = (const half8_t*)syj_h;
        half8_t a0 = ap[q];           // k = q*8 ..
        half8_t a1 = ap[4 + q];       // k = 32 + q*8 ..
        float4_t acc0 = MFMA16(a0, bW1[0], Zv);
        float4_t acc1 = MFMA16(a1, bW1[1], Zv);
        if (q == 0) sh1h[n1] = (half_t)softplus_f(acc0[0] + acc1[0] + bf1r);
      }
      BAR_LDS();   // B1

      // ---- h2: h1 @ Wf2^T (K=128), fp16 MFMA; output quantized to int8 ----
      {
        const half8_t* ap = (const half8_t*)sh1h;
        half8_t a0 = ap[q], a1 = ap[4 + q], a2 = ap[8 + q], a3 = ap[12 + q];
        float4_t accA = MFMA16(a0, bW2[0], Zv);
        float4_t accB = MFMA16(a1, bW2[1], Zv);
        accA = MFMA16(a2, bW2[2], accA);
        accB = MFMA16(a3, bW2[3], accB);
        if (q == 0) {
          const float h2v = softplus_f(accA[0] + accB[0] + bf2r);
          const int qi = (int)(fminf(h2v, H2B) * (127.0f / H2B) + 0.5f);
          sh2b[n1] = (unsigned char)qi;
        }
      }
      BAR_LDS();   // B2

      // ---- GEMV3: FULL v_dot4_i32_i8, exact int (no MFMA, no quad-select) ----
      {
        // broadcast-read all 128 bytes of h2 (uniform address, conflict-free)
        int hti[32];
        {
          const int4v* hp = (const int4v*)(&sh2b[0]);
          #pragma unroll
          for (int i = 0; i < 8; ++i) ((int4v*)hti)[i] = hp[i];
        }
        // 8 independent accumulator chains (2 outputs x 4), 8 dot4 each
        int d0a = 0, d0b = 0, d0c = 0, d0d = 0;
        int d1a = 0, d1b = 0, d1c = 0, d1d = 0;
        #pragma unroll
        for (int i = 0; i < 8; ++i) {
          d0a = dot4i(w3t0[i],      hti[i],      d0a);
          d1a = dot4i(w3t1[i],      hti[i],      d1a);
          d0b = dot4i(w3t0[i + 8],  hti[i + 8],  d0b);
          d1b = dot4i(w3t1[i + 8],  hti[i + 8],  d1b);
          d0c = dot4i(w3t0[i + 16], hti[i + 16], d0c);
          d1c = dot4i(w3t1[i + 16], hti[i + 16], d1c);
          d0d = dot4i(w3t0[i + 24], hti[i + 24], d0d);
          d1d = dot4i(w3t1[i + 24], hti[i + 24], d1d);
        }
        const int i0 = (d0a + d0b) + (d0c + d0d);
        const int i1 = (d1a + d1b) + (d1c + d1d);
        const float v0 = (float)i0 * sw0s;
        const float v1 = (float)i1 * sw1s;

        const float dx = dxj[j];
        float p0 = tanh_f(v0 + bf3r0) * dx;
        float p1 = tanh_f(v1 + bf3r1) * dx;
        // 16-lane butterfly via DPP
        p0 = DPP_ADD(p0, 0xB1);   p1 = DPP_ADD(p1, 0xB1);
        p0 = DPP_ADD(p0, 0x4E);   p1 = DPP_ADD(p1, 0x4E);
        p0 = DPP_ADD(p0, 0x141);  p1 = DPP_ADD(p1, 0x141);
        p0 = DPP_ADD(p0, 0x140);  p1 = DPP_ADD(p1, 0x140);

        // wave-uniform RK arithmetic
        kr0[j] = p0;
        kr1[j] = p1;
        float sa0 = AE[j][0] * kr0[0];
        float sa1 = AE[j][0] * kr1[0];
        #pragma unroll
        for (int m = 1; m < 6; ++m) if (m <= j) { sa0 = fmaf(AE[j][m], kr0[m], sa0); sa1 = fmaf(AE[j][m], kr1[m], sa1); }
        float yn0 = fmaf(hstep, sa0, yr0);
        float yn1 = fmaf(hstep, sa1, yr1);
        if (j == 5) { yr0 = yn0; yr1 = yn1; }
        if (c == 0) {
          half2_t p; p[0] = (half_t)yn0; p[1] = (half_t)yn1;
          *(half2_t*)(syj_h + s0) = p;
          if (j == 5) {
            float2 f; f.x = yn0; f.y = yn1;
            *(float2*)(&shist[t + 1][s0]) = f;
          }
        }
      }
      BAR_LDS();   // B3
    }

    cbv = cbn; ccv = ccn; cdv = cdn;
  }

  // ---- batched projection epilogue: out[b, t, o] for all 64 t x 8 o ----
  __syncthreads();
  {
    const int tt = tid >> 3;       // 0..63
    const int oo = tid & 7;        // 0..7
    const float4* yp = (const float4*)(&shist[tt][0]);
    const float4* wp = (const float4*)(sWr + oo * S_);
    float a0 = 0.f, a1 = 0.f;
    #pragma unroll
    for (int i = 0; i < 16; i += 2) {
      float4 y0 = yp[i], w0 = wp[i];
      float4 y1 = yp[i + 1], w1 = wp[i + 1];
      a0 += y0.x * w0.x + y0.y * w0.y + y0.z * w0.z + y0.w * w0.w;
      a1 += y1.x * w1.x + y1.y * w1.y + y1.z * w1.z + y1.w * w1.w;
    }
    out[((size_t)b * T_ + tt) * O_ + oo] = a0 + a1 + sbr[oo];
  }
}

extern "C" void kernel_launch(void* const* d_in, const int* in_sizes, int n_in,
                              void* d_out, int out_size, void* d_ws, size_t ws_size,
                              hipStream_t stream) {
  const float* ts  = (const float*)d_in[0];
  const float* cd  = (const float*)d_in[1];
  const float* cc  = (const float*)d_in[2];
  const float* cb  = (const float*)d_in[3];
  const float* ca  = (const float*)d_in[4];
  const float* Wi1 = (const float*)d_in[5];
  const float* bi1 = (const float*)d_in[6];
  const float* Wi2 = (const float*)d_in[7];
  const float* bi2 = (const float*)d_in[8];
  const float* Wf1 = (const float*)d_in[9];
  const float* bf1 = (const float*)d_in[10];
  const float* Wf2 = (const float*)d_in[11];
  const float* bf2 = (const float*)d_in[12];
  const float* Wf3 = (const float*)d_in[13];
  const float* bf3 = (const float*)d_in[14];
  const float* Wr  = (const float*)d_in[15];
  const float* br  = (const float*)d_in[16];

  unsigned char* wsb = (unsigned char*)d_ws;
  hipLaunchKernelGGL(convert12_kernel, dim3(96), dim3(256), 0, stream, Wf1, Wf2, wsb);
  hipLaunchKernelGGL(convert3_kernel, dim3(256), dim3(256), 0, stream, Wf3, wsb);
  hipLaunchKernelGGL(cde_kernel_i8d4, dim3(B_), dim3(NT), 0, stream,
                     ts, cd, cc, cb, ca, Wi1, bi1, Wi2, bi2,
                     bf1, bf2, bf3, Wr, br, wsb, (float*)d_out);
}

// Round 10
// 420.757 us; speedup vs baseline: 5.2983x; 1.0938x over previous
//
#include <hip/hip_runtime.h>
#include <math.h>

typedef _Float16 half_t;
typedef _Float16 half2_t __attribute__((ext_vector_type(2)));
typedef _Float16 half8_t __attribute__((ext_vector_type(8)));
typedef float float4_t __attribute__((ext_vector_type(4)));
typedef int int4v __attribute__((ext_vector_type(4)));

#define T_ 64
#define B_ 256
#define D_ 16
#define S_ 64
#define SP_ 68   // padded y-history row stride (floats)
#define H_ 128
#define O_ 8
#define NSTEP 63
#define NT 512

// ws layout (bytes):
//   [0, 131072)        Wf3 int8, row-major [1024][128]
//   [131072, 135168)   swf  float[1024] per-row scales for Wf3 (max|row|/127)
//   [135168, 151552)   Wf1  fp16 [128][64]
//   [151552, 167936)   Wf2  int8 [128][128]
//   [167936, 168448)   swf2 float[128] per-row scales for Wf2
#define W3I_OFF  0
#define SWF_OFF  131072
#define W1_OFF   135168
#define W2I_OFF  151552
#define SWF2_OFF 167936

#define H2B 8.0f    // clamp bound for h2 int8 quantization (derived bound ~3)
#define H1B 16.0f   // clamp bound for h1 int8 quantization (h1 ~ sigma 1.7; 16 = 9 sigma)

#define MFMA16(a, b, c) __builtin_amdgcn_mfma_f32_16x16x32_f16(a, b, c, 0, 0, 0)
#define MFMAI8(a, b, c) __builtin_amdgcn_mfma_i32_16x16x64_i8(a, b, c, 0, 0, 0)

// LDS-only barrier (R4-validated): wait ds ops, sync, fence compiler.
#define BAR_LDS() do { \
  asm volatile("s_waitcnt lgkmcnt(0)" ::: "memory"); \
  __builtin_amdgcn_s_barrier(); \
  asm volatile("" ::: "memory"); \
} while (0)

// DPP 16-lane butterfly add (VALU; validated)
#if __has_builtin(__builtin_amdgcn_mov_dpp)
#define DPP_ADD(x, ctrl) \
  ((x) + __int_as_float(__builtin_amdgcn_mov_dpp(__float_as_int(x), (ctrl), 0xF, 0xF, true)))
#else
#define DPP_ADD(x, ctrl) ((x) + __shfl_xor((x), (ctrl) == 0xB1 ? 1 : (ctrl) == 0x4E ? 2 : (ctrl) == 0x141 ? 4 : 8))
#endif

// AE[j] = coefficients on k[0..j] producing the NEXT stage input (j<5) or B_SOL (j==5)
__device__ constexpr float AE[6][6] = {
  {0.161f, 0.f, 0.f, 0.f, 0.f, 0.f},
  {-0.008480655492356989f, 0.335480655492357f, 0.f, 0.f, 0.f, 0.f},
  {2.8971530571054935f, -6.359448489975075f, 4.3622954328695815f, 0.f, 0.f, 0.f},
  {5.325864828439257f, -11.748883564062828f, 7.4955393428898365f, -0.09249506636175525f, 0.f, 0.f},
  {5.86145544294642f, -12.92096931784711f, 8.159367898576159f, -0.071584973281401f, -0.028269050394068383f, 0.f},
  {0.09646076681806523f, 0.01f, 0.4798896504144996f, 1.379008574103742f, -3.290069515436081f, 2.324710524099774f}
};
__device__ constexpr float CCn[6] = {0.f, 0.161f, 0.327f, 0.9f, 0.9800255409045097f, 1.f};

__device__ __forceinline__ float softplus_f(float x) {
  return fmaxf(x, 0.f) + __logf(1.f + __expf(-fabsf(x)));
}
__device__ __forceinline__ float tanh_f(float x) {
  float xc = fminf(fmaxf(x, -12.f), 12.f);
  float e = __expf(2.f * xc);
  return (e - 1.f) * __builtin_amdgcn_rcpf(e + 1.f);
}

// ---------------- prologue 1: Wf1 fp32 -> fp16 ----------------
__global__ __launch_bounds__(256) void convert1_kernel(
    const float* __restrict__ Wf1, unsigned char* __restrict__ wsb)
{
  half_t* w1h = (half_t*)(wsb + W1_OFF);
  int q = blockIdx.x * 256 + threadIdx.x;
  if (q < 8192) w1h[q] = (half_t)Wf1[q];
}

// ---------------- prologue 2: Wf3 + Wf2 fp32 -> int8 with per-row scales ----------------
// 288 blocks x 4 waves; rows 0..1023 = Wf3, rows 1024..1151 = Wf2 (all 128-wide).
__global__ __launch_bounds__(256) void convert32_kernel(
    const float* __restrict__ Wf3, const float* __restrict__ Wf2,
    unsigned char* __restrict__ wsb)
{
  signed char* w3i = (signed char*)(wsb + W3I_OFF);
  float* swf = (float*)(wsb + SWF_OFF);
  signed char* w2i = (signed char*)(wsb + W2I_OFF);
  float* swf2 = (float*)(wsb + SWF2_OFF);
  const int tid = threadIdx.x;
  const int wid = tid >> 6;
  const int lane = tid & 63;
  const int row = blockIdx.x * 4 + wid;
  const float* src;
  signed char* dst;
  float* sdst;
  if (row < 1024) { src = Wf3 + (size_t)row * H_; dst = w3i + (size_t)row * H_; sdst = swf + row; }
  else { const int r2 = row - 1024; src = Wf2 + (size_t)r2 * H_; dst = w2i + (size_t)r2 * H_; sdst = swf2 + r2; }
  const float a0 = src[2 * lane];
  const float a1 = src[2 * lane + 1];
  float m = fmaxf(fabsf(a0), fabsf(a1));
  #pragma unroll
  for (int s = 1; s < 64; s <<= 1) m = fmaxf(m, __shfl_xor(m, s));
  const float sw = fmaxf(m, 1e-20f) * (1.0f / 127.0f);
  const float inv = 1.0f / sw;
  dst[2 * lane]     = (signed char)(int)floorf(a0 * inv + 0.5f);
  dst[2 * lane + 1] = (signed char)(int)floorf(a1 * inv + 0.5f);
  if (lane == 0) *sdst = sw;
}

// ---------------- main kernel ----------------
// R5 structure (the 355 us best) with the h2 GEMV also moved to int8 MFMA:
//   h1: fp16 MFMA (K=64) -> softplus -> quantize to uint8 (clamp H1B)
//   h2: 2x mfma_i32_16x16x64_i8 (was 4x f16 MFMA) with per-Wf2-row scales
//   G3: 16x i8 MFMA (R5-proven optimal for this structure)
// Matrix/stage drops ~78 cyc/SIMD; h1-quant adds ~4 masked VALU ops.
__global__ void __launch_bounds__(NT) __attribute__((amdgpu_waves_per_eu(2, 2)))
cde_kernel_i8h2(
    const float* __restrict__ ts,
    const float* __restrict__ coeff_d,
    const float* __restrict__ coeff_c,
    const float* __restrict__ coeff_b,
    const float* __restrict__ coeff_a,
    const float* __restrict__ Wi1, const float* __restrict__ bi1,
    const float* __restrict__ Wi2, const float* __restrict__ bi2,
    const float* __restrict__ bf1, const float* __restrict__ bf2,
    const float* __restrict__ bf3,
    const float* __restrict__ Wr, const float* __restrict__ br,
    const unsigned char* __restrict__ wsb,
    float* __restrict__ out)
{
  __shared__ __align__(16) half_t syj_h[S_];
  __shared__ __align__(16) unsigned char sh1b[H_];   // h1 quantized uint8 (0..127)
  __shared__ __align__(16) unsigned char sh2b[H_];   // h2 quantized uint8 (0..127)
  __shared__ __align__(16) float shist[T_][SP_];     // y history (padded rows)
  __shared__ float sWr[O_ * S_];
  __shared__ float sbr[O_];
  __shared__ float sx0[D_];
  __shared__ float sini[H_];
  __shared__ float shs[T_];

  const int tid = threadIdx.x;
  const int b = blockIdx.x;
  const int w = tid >> 6;          // wave 0..7
  const int lane = tid & 63;
  const int q = lane >> 4;         // 16-lane row 0..3
  const int c = lane & 15;         // fragment column

  const signed char* __restrict__ w3i = (const signed char*)(wsb + W3I_OFF);
  const float* __restrict__ swf = (const float*)(wsb + SWF_OFF);
  const half_t* __restrict__ w1p = (const half_t*)(wsb + W1_OFF);
  const signed char* __restrict__ w2i = (const signed char*)(wsb + W2I_OFF);
  const float* __restrict__ swf2 = (const float*)(wsb + SWF2_OFF);

  // ---- persistent B fragments ----
  const int n1 = 16 * w + c;       // output column for h1/h2 tiles
  half8_t bW1[2];
  int4v bW2i[2], bW3i[8][2];
  #pragma unroll
  for (int ks = 0; ks < 2; ++ks)
    bW1[ks] = *(const half8_t*)(w1p + n1 * S_ + ks * 32 + q * 8);
  #pragma unroll
  for (int ks = 0; ks < 2; ++ks)
    bW2i[ks] = *(const int4v*)(w2i + (size_t)n1 * H_ + ks * 64 + q * 16);
  #pragma unroll
  for (int t = 0; t < 8; ++t) {
    const int r = 16 * (8 * w + t) + c;   // Wf3 row for this tile/col
    #pragma unroll
    for (int ks = 0; ks < 2; ++ks)
      bW3i[t][ks] = *(const int4v*)(w3i + (size_t)r * H_ + ks * 64 + q * 16);
  }
  const float bf1r = bf1[n1];
  const float bf2r = bf2[n1];
  // h2 dequant scale: W2 row scale x h1 activation scale (H1B/127)
  const float sw2s = swf2[n1] * (H1B / 127.0f);
  // epilogue rows this lane keeps: s0 = 8w+2q, s1 = s0+1 (col c = d)
  const int s0 = 8 * w + 2 * q;
  const float bf3r0 = bf3[16 * s0 + c];
  const float bf3r1 = bf3[16 * (s0 + 1) + c];
  const float sw0s = swf[16 * s0 + c] * (H2B / 127.0f);
  const float sw1s = swf[16 * (s0 + 1) + c] * (H2B / 127.0f);

  // ---- one-time staging + y0 ----
  if (tid < O_ * S_) sWr[tid] = Wr[tid];
  if (tid < O_) sbr[tid] = br[tid];
  if (tid < D_) sx0[tid] = coeff_a[(size_t)b * NSTEP * D_ + tid];
  if (tid < NSTEP) shs[tid] = ts[tid + 1] - ts[tid];
  __syncthreads();
  if (tid < H_) {
    float acc = bi1[tid];
    #pragma unroll
    for (int d = 0; d < D_; ++d) acc += sx0[d] * Wi1[tid * D_ + d];
    sini[tid] = softplus_f(acc);
  }
  __syncthreads();
  if (tid < S_) {
    float acc = bi2[tid];
    for (int h = 0; h < H_; ++h) acc += sini[h] * Wi2[tid * H_ + h];
    shist[0][tid] = acc;
  }
  __syncthreads();

  // RK state wave-uniform per 16-lane row: all lanes of row q track y[s0], y[s0+1]
  float yr0 = shist[0][s0];
  float yr1 = shist[0][s0 + 1];
  float kr0[6] = {0.f,0.f,0.f,0.f,0.f,0.f};
  float kr1[6] = {0.f,0.f,0.f,0.f,0.f,0.f};
  if (c == 0) {
    half2_t p; p[0] = (half_t)yr0; p[1] = (half_t)yr1;
    *(half2_t*)(syj_h + s0) = p;
  }
  __syncthreads();

  const float4_t Zv = {0.f, 0.f, 0.f, 0.f};
  const int4v Zi = {0, 0, 0, 0};

  // coeff register pipeline (R4): values for step t in (cbv,ccv,cdv); prefetch t+1
  const size_t cbase = (size_t)b * NSTEP * D_ + c;
  float cbv = coeff_b[cbase];
  float ccv = coeff_c[cbase];
  float cdv = coeff_d[cbase];

  // ---- time loop ----
  for (int t = 0; t < NSTEP; ++t) {
    const int tn = (t + 1 < NSTEP) ? (t + 1) : t;
    const size_t cidxn = cbase + (size_t)tn * D_;
    const float cbn = coeff_b[cidxn];
    const float ccn = coeff_c[cidxn];
    const float cdn = coeff_d[cidxn];

    const float hstep = shs[t];
    float dxj[6];
    #pragma unroll
    for (int j = 0; j < 6; ++j) {
      const float frac = CCn[j] * hstep;
      dxj[j] = cbv + frac * (2.f * ccv + 3.f * frac * cdv);
    }

    #pragma unroll
    for (int j = 0; j < 6; ++j) {
      // ---- h1: yj @ Wf1^T (K=64), fp16 MFMA; output quantized to uint8 ----
      {
        const half8_t* ap = (const half8_t*)syj_h;
        half8_t a0 = ap[q];           // k = q*8 ..
        half8_t a1 = ap[4 + q];       // k = 32 + q*8 ..
        float4_t acc0 = MFMA16(a0, bW1[0], Zv);
        float4_t acc1 = MFMA16(a1, bW1[1], Zv);
        if (q == 0) {
          const float h1v = softplus_f(acc0[0] + acc1[0] + bf1r);
          const int qi = (int)(fminf(h1v, H1B) * (127.0f / H1B) + 0.5f);
          sh1b[n1] = (unsigned char)qi;
        }
      }
      BAR_LDS();   // B1

      // ---- h2: h1 @ Wf2^T (K=128), int8 MFMA x2; output quantized to uint8 ----
      {
        const int4v a0i = *(const int4v*)(sh1b + 16 * q);        // k = 0..63
        const int4v a1i = *(const int4v*)(sh1b + 64 + 16 * q);   // k = 64..127
        int4v iacc = MFMAI8(a0i, bW2i[0], Zi);
        iacc = MFMAI8(a1i, bW2i[1], iacc);
        if (q == 0) {
          const float h2v = softplus_f((float)iacc[0] * sw2s + bf2r);
          const int qi = (int)(fminf(h2v, H2B) * (127.0f / H2B) + 0.5f);
          sh2b[n1] = (unsigned char)qi;
        }
      }
      BAR_LDS();   // B2

      // ---- GEMV3: int8 MFMA, 8 tiles x 2 K-slices (R5-proven optimal) ----
      {
        const int4v a0i = *(const int4v*)(sh2b + 16 * q);        // k = 0..63
        const int4v a1i = *(const int4v*)(sh2b + 64 + 16 * q);   // k = 64..127
        int4v iacc[8];
        #pragma unroll
        for (int tt = 0; tt < 8; ++tt) iacc[tt] = MFMAI8(a0i, bW3i[tt][0], Zi);
        #pragma unroll
        for (int tt = 0; tt < 8; ++tt) iacc[tt] = MFMAI8(a1i, bW3i[tt][1], iacc[tt]);

        // quad q consumes tiles 2q, 2q+1 (rows s0, s0+1 at col c)
        int i0, i1;
        if (q == 0)      { i0 = iacc[0][0]; i1 = iacc[1][0]; }
        else if (q == 1) { i0 = iacc[2][0]; i1 = iacc[3][0]; }
        else if (q == 2) { i0 = iacc[4][0]; i1 = iacc[5][0]; }
        else             { i0 = iacc[6][0]; i1 = iacc[7][0]; }
        const float v0 = (float)i0 * sw0s;
        const float v1 = (float)i1 * sw1s;

        const float dx = dxj[j];
        float p0 = tanh_f(v0 + bf3r0) * dx;
        float p1 = tanh_f(v1 + bf3r1) * dx;
        // 16-lane butterfly via DPP
        p0 = DPP_ADD(p0, 0xB1);   p1 = DPP_ADD(p1, 0xB1);
        p0 = DPP_ADD(p0, 0x4E);   p1 = DPP_ADD(p1, 0x4E);
        p0 = DPP_ADD(p0, 0x141);  p1 = DPP_ADD(p1, 0x141);
        p0 = DPP_ADD(p0, 0x140);  p1 = DPP_ADD(p1, 0x140);

        // wave-uniform RK arithmetic
        kr0[j] = p0;
        kr1[j] = p1;
        float sa0 = AE[j][0] * kr0[0];
        float sa1 = AE[j][0] * kr1[0];
        #pragma unroll
        for (int m = 1; m < 6; ++m) if (m <= j) { sa0 = fmaf(AE[j][m], kr0[m], sa0); sa1 = fmaf(AE[j][m], kr1[m], sa1); }
        float yn0 = fmaf(hstep, sa0, yr0);
        float yn1 = fmaf(hstep, sa1, yr1);
        if (j == 5) { yr0 = yn0; yr1 = yn1; }
        if (c == 0) {
          half2_t p; p[0] = (half_t)yn0; p[1] = (half_t)yn1;
          *(half2_t*)(syj_h + s0) = p;
          if (j == 5) {
            float2 f; f.x = yn0; f.y = yn1;
            *(float2*)(&shist[t + 1][s0]) = f;
          }
        }
      }
      BAR_LDS();   // B3
    }

    cbv = cbn; ccv = ccn; cdv = cdn;
  }

  // ---- batched projection epilogue: out[b, t, o] for all 64 t x 8 o ----
  __syncthreads();
  {
    const int tt = tid >> 3;       // 0..63
    const int oo = tid & 7;        // 0..7
    const float4* yp = (const float4*)(&shist[tt][0]);
    const float4* wp = (const float4*)(sWr + oo * S_);
    float a0 = 0.f, a1 = 0.f;
    #pragma unroll
    for (int i = 0; i < 16; i += 2) {
      float4 y0 = yp[i], w0 = wp[i];
      float4 y1 = yp[i + 1], w1 = wp[i + 1];
      a0 += y0.x * w0.x + y0.y * w0.y + y0.z * w0.z + y0.w * w0.w;
      a1 += y1.x * w1.x + y1.y * w1.y + y1.z * w1.z + y1.w * w1.w;
    }
    out[((size_t)b * T_ + tt) * O_ + oo] = a0 + a1 + sbr[oo];
  }
}

extern "C" void kernel_launch(void* const* d_in, const int* in_sizes, int n_in,
                              void* d_out, int out_size, void* d_ws, size_t ws_size,
                              hipStream_t stream) {
  const float* ts  = (const float*)d_in[0];
  const float* cd  = (const float*)d_in[1];
  const float* cc  = (const float*)d_in[2];
  const float* cb  = (const float*)d_in[3];
  const float* ca  = (const float*)d_in[4];
  const float* Wi1 = (const float*)d_in[5];
  const float* bi1 = (const float*)d_in[6];
  const float* Wi2 = (const float*)d_in[7];
  const float* bi2 = (const float*)d_in[8];
  const float* Wf1 = (const float*)d_in[9];
  const float* bf1 = (const float*)d_in[10];
  const float* Wf2 = (const float*)d_in[11];
  const float* bf2 = (const float*)d_in[12];
  const float* Wf3 = (const float*)d_in[13];
  const float* bf3 = (const float*)d_in[14];
  const float* Wr  = (const float*)d_in[15];
  const float* br  = (const float*)d_in[16];

  unsigned char* wsb = (unsigned char*)d_ws;
  hipLaunchKernelGGL(convert1_kernel, dim3(32), dim3(256), 0, stream, Wf1, wsb);
  hipLaunchKernelGGL(convert32_kernel, dim3(288), dim3(256), 0, stream, Wf3, Wf2, wsb);
  hipLaunchKernelGGL(cde_kernel_i8h2, dim3(B_), dim3(NT), 0, stream,
                     ts, cd, cc, cb, ca, Wi1, bi1, Wi2, bi2,
                     bf1, bf2, bf3, Wr, br, wsb, (float*)d_out);
}